// Round 11
// baseline (559.816 us; speedup 1.0000x reference)
//
#include <hip/hip_runtime.h>
#include <hip/hip_bf16.h>
#include <stdint.h>

typedef unsigned short u16;
typedef _Float16 f16;
typedef short vs8 __attribute__((ext_vector_type(8)));   // 8 x bf16 bits (MFMA A/B frag)
typedef float vf4 __attribute__((ext_vector_type(4)));   // MFMA C/D frag
typedef _Float16 vh2 __attribute__((ext_vector_type(2)));
typedef _Float16 vh4 __attribute__((ext_vector_type(4)));
typedef _Float16 vh8 __attribute__((ext_vector_type(8)));
typedef __fp16 hw2 __attribute__((ext_vector_type(2)));  // cvt_pkrtz return type

// Problem constants: B=4 T=2048 E=256 H=8 HD=32 FE=4 L=4

__device__ __forceinline__ void gload16(const u16* g, u16* l) {
  __builtin_amdgcn_global_load_lds((const __attribute__((address_space(1))) void*)g,
                                   (__attribute__((address_space(3))) void*)l,
                                   16, 0, 0);
}

__device__ __forceinline__ float fexp2(float x) {
#if __has_builtin(__builtin_amdgcn_exp2f)
  return __builtin_amdgcn_exp2f(x);
#else
  return __expf(x * 0.69314718056f);
#endif
}

// ---------------- Fourier PE -> bf16 only ----------------
__global__ void pe_kernel(const float* __restrict__ x, __hip_bfloat16* __restrict__ Xb) {
  int row = blockIdx.x;            // b*2048 + t
  int e = threadIdx.x;             // 0..255
  int t = row & 2047;
  int f = (e < 128) ? e : (e - 128);
  float freq = powf(10000.0f, -(float)f * (1.0f / 128.0f));
  float arg = (float)t * freq;
  float pe = (e < 128) ? sinf(arg) : cosf(arg);
  size_t idx = (size_t)row * 256 + e;
  Xb[idx] = __float2bfloat16(x[idx] + pe);
}

// ---------------- weight transpose + cast: in[L][K][N] f32 -> out[L][N][K] (bf16 or f16) ----------------
__global__ void transpose_cast(const float* __restrict__ in, u16* __restrict__ out,
                               int K, int N, int as_f16) {
  __shared__ float tile[32][33];
  int layer = blockIdx.z;
  int k0 = blockIdx.x * 32, n0 = blockIdx.y * 32;
  const float* ip = in + (size_t)layer * K * N;
  u16* op = out + (size_t)layer * N * K;
  int tx = threadIdx.x, ty = threadIdx.y;   // (32,8)
#pragma unroll
  for (int r = 0; r < 4; ++r) {
    int k = ty + r * 8;
    tile[k][tx] = ip[(size_t)(k0 + k) * N + (n0 + tx)];
  }
  __syncthreads();
#pragma unroll
  for (int r = 0; r < 4; ++r) {
    int n = ty + r * 8;
    float val = tile[tx][n];
    u16 bits;
    if (as_f16) { f16 v = (f16)val; bits = *(u16*)&v; }
    else        { __hip_bfloat16 v = __float2bfloat16(val); bits = *(u16*)&v; }
    op[(size_t)(n0 + n) * K + (k0 + tx)] = bits;
  }
}

// ---------------- bf16 MFMA GEMM 64x128 (qkv): C = A@W + bias -> f16 ----------------
__global__ __launch_bounds__(256, 2) void gemm_qkv(
    const u16* __restrict__ A, const u16* __restrict__ Bt,
    const float* __restrict__ bias, f16* __restrict__ outH,
    int M, int N, int K) {
  __shared__ u16 As[64 * 32];
  __shared__ u16 Bs[128 * 32];
  int tid = threadIdx.x;
  int wave = tid >> 6, lane = tid & 63;
  int wm = wave & 1, wn = wave >> 1;              // wave = 32 rows x 64 cols
  int m0 = blockIdx.y * 64, n0 = blockIdx.x * 128;
  int lr = lane & 15, lq = lane >> 4;

  vf4 acc[2][4];
#pragma unroll
  for (int i = 0; i < 2; ++i)
#pragma unroll
    for (int j = 0; j < 4; ++j) { acc[i][j][0]=0.f; acc[i][j][1]=0.f; acc[i][j][2]=0.f; acc[i][j][3]=0.f; }

  int sr = tid >> 2, sc = (tid & 3) * 8;
  const u16* ag = A + (size_t)(m0 + sr) * K + sc;
  const u16* bg = Bt + (size_t)(n0 + sr) * K + sc;
  u16* al = As + sr * 32 + sc;
  u16* bl = Bs + sr * 32 + sc;

  for (int k0 = 0; k0 < K; k0 += 32) {
    gload16(ag + k0, al);
    gload16(bg + k0, bl);
    gload16(bg + k0 + (size_t)64 * K, bl + 64 * 32);
    __syncthreads();
    vs8 av[2], bv[4];
#pragma unroll
    for (int i = 0; i < 2; ++i)
      av[i] = *(const vs8*)&As[(wm * 32 + i * 16 + lr) * 32 + lq * 8];
#pragma unroll
    for (int j = 0; j < 4; ++j)
      bv[j] = *(const vs8*)&Bs[(wn * 64 + j * 16 + lr) * 32 + lq * 8];
#pragma unroll
    for (int i = 0; i < 2; ++i)
#pragma unroll
      for (int j = 0; j < 4; ++j)
        acc[i][j] = __builtin_amdgcn_mfma_f32_16x16x32_bf16(av[i], bv[j], acc[i][j], 0, 0, 0);
    __syncthreads();
  }

#pragma unroll
  for (int i = 0; i < 2; ++i) {
    int row0 = m0 + wm * 32 + i * 16 + lq * 4;
#pragma unroll
    for (int j = 0; j < 4; ++j) {
      int col = n0 + wn * 64 + j * 16 + lr;
      float bb = bias[col];
#pragma unroll
      for (int r = 0; r < 4; ++r)
        outH[(size_t)(row0 + r) * N + col] = (f16)(acc[i][j][r] + bb);
    }
  }
}

// ---------------- fused GEMM (N=256) + bias + bf16 residual + LayerNorm -> bf16 ----------------
__global__ __launch_bounds__(256, 2) void gemm_ln(
    const u16* __restrict__ A, const u16* __restrict__ Bt,
    const float* __restrict__ bias, const __hip_bfloat16* __restrict__ res,
    const float* __restrict__ gam, const float* __restrict__ bet,
    __hip_bfloat16* __restrict__ outB, int K) {
  __shared__ u16 As[32 * 32];
  __shared__ u16 Bs[256 * 32];
  __shared__ float ps[2][32], ps2[2][32], mur[32], rsr[32];
  int tid = threadIdx.x;
  int wave = tid >> 6, lane = tid & 63;
  int wm = wave & 1, wn = wave >> 1;
  int lr = lane & 15, lq = lane >> 4;
  int m0 = blockIdx.x * 32;

  vf4 acc[8];
#pragma unroll
  for (int j = 0; j < 8; ++j) { acc[j][0]=0.f; acc[j][1]=0.f; acc[j][2]=0.f; acc[j][3]=0.f; }

  int sr = tid >> 2, sc = (tid & 3) * 8;
  const u16* ag = A + (size_t)(m0 + sr) * K + sc;
  const u16* bg = Bt + (size_t)sr * K + sc;
  u16* al = As + sr * 32 + sc;
  u16* bl = Bs + sr * 32 + sc;

  for (int k0 = 0; k0 < K; k0 += 32) {
    if (tid < 128) gload16(ag + k0, al);
#pragma unroll
    for (int r = 0; r < 4; ++r)
      gload16(bg + k0 + (size_t)64 * r * K, bl + 64 * r * 32);
    __syncthreads();
    vs8 av, bv[8];
    av = *(const vs8*)&As[(wm * 16 + lr) * 32 + lq * 8];
#pragma unroll
    for (int j = 0; j < 8; ++j)
      bv[j] = *(const vs8*)&Bs[(wn * 128 + j * 16 + lr) * 32 + lq * 8];
#pragma unroll
    for (int j = 0; j < 8; ++j)
      acc[j] = __builtin_amdgcn_mfma_f32_16x16x32_bf16(av, bv[j], acc[j], 0, 0, 0);
    __syncthreads();
  }

  float sum_[4], sq_[4];
#pragma unroll
  for (int r = 0; r < 4; ++r) { sum_[r] = 0.f; sq_[r] = 0.f; }
#pragma unroll
  for (int j = 0; j < 8; ++j) {
    int col = wn * 128 + j * 16 + lr;
    float bb = bias[col];
#pragma unroll
    for (int r = 0; r < 4; ++r) {
      int row = m0 + wm * 16 + lq * 4 + r;
      float v = acc[j][r] + bb + __bfloat162float(res[(size_t)row * 256 + col]);
      acc[j][r] = v;
      sum_[r] += v;
      sq_[r] += v * v;
    }
  }
#pragma unroll
  for (int r = 0; r < 4; ++r) {
#pragma unroll
    for (int m = 1; m <= 8; m <<= 1) {
      sum_[r] += __shfl_xor(sum_[r], m);
      sq_[r]  += __shfl_xor(sq_[r], m);
    }
  }
  if (lr == 0) {
#pragma unroll
    for (int r = 0; r < 4; ++r) {
      int rl = wm * 16 + lq * 4 + r;
      ps[wn][rl] = sum_[r];
      ps2[wn][rl] = sq_[r];
    }
  }
  __syncthreads();
  if (tid < 32) {
    float s = ps[0][tid] + ps[1][tid];
    float s2 = ps2[0][tid] + ps2[1][tid];
    float mu = s * (1.0f / 256.0f);
    float var = s2 * (1.0f / 256.0f) - mu * mu;
    mur[tid] = mu;
    rsr[tid] = rsqrtf(var + 1e-5f);
  }
  __syncthreads();
#pragma unroll
  for (int r = 0; r < 4; ++r) {
    int rl = wm * 16 + lq * 4 + r;
    float mu = mur[rl], rs = rsr[rl];
    int row = m0 + rl;
#pragma unroll
    for (int j = 0; j < 8; ++j) {
      int col = wn * 128 + j * 16 + lr;
      float o = (acc[j][r] - mu) * rs * gam[col] + bet[col];
      outB[(size_t)row * 256 + col] = __float2bfloat16(o);
    }
  }
}

// ---------------- fused FFN v3: frag-major LDS (zero-conflict reads) + double buffer ----------------
// W1/W2 LDS tiles stored FRAGMENT-MAJOR: hot-loop frag reads are exactly lane-linear
// (addr=(s*64+lane)*16B for W1 b128, (nt*64+lane)*8B for W2 b64) — zero bank conflicts
// by construction (R9 layouts were 8-way: 7.47M conflict cycles). Double buffer, 1 barrier/chunk.
// LDS: buf[2] x (W1f 2ph*4096 u16 | W2f 2ph*4096 f16) = 2*16384 u16; b1s f32 @32768 u16.
__global__ __launch_bounds__(256, 2) void ffn_fused(
    const u16* __restrict__ Xb, const u16* __restrict__ W1t, const float* __restrict__ b1,
    const f16* __restrict__ W2t, const float* __restrict__ b2,
    const float* __restrict__ gam, const float* __restrict__ bet,
    __hip_bfloat16* __restrict__ outB, float* __restrict__ outF) {
  __shared__ __align__(16) u16 lds[34816];          // 69,632 B
  float* b1s = (float*)(lds + 32768);
  float* mergef = (float*)lds;                       // post-loop overlay [2][16][257] f32

  int tid = threadIdx.x;
  int wave = tid >> 6, lane = tid & 63;
  int lr = lane & 15, quad = lane >> 4;
  int mh = wave & 1, ph = wave >> 1;
  int m0 = blockIdx.x * 32;

  // x B-frags (bf16) for this wave's 16 rows — loaded once
  vs8 xv[8];
#pragma unroll
  for (int s = 0; s < 8; ++s)
    xv[s] = *(const vs8*)&Xb[(size_t)(m0 + mh * 16 + lr) * 256 + s * 32 + quad * 8];

  vf4 acc2[16];
#pragma unroll
  for (int j = 0; j < 16; ++j) { acc2[j][0]=0.f; acc2[j][1]=0.f; acc2[j][2]=0.f; acc2[j][3]=0.f; }

  // staging maps (waves 0-1: phs0, waves 2-3: phs1)
  int phs = tid >> 7, t7 = tid & 127;
  int w1row = t7 >> 3, w1seg = t7 & 7;              // W1: 16 rows x 64B/thread
  const u16* w1g = W1t + (size_t)(phs * 512 + w1row) * 256 + w1seg * 32;   // + c*16*256
  int n2a = t7 * 2, n2b = t7 * 2 + 1;               // W2: 2 rows x 32B/thread
  const f16* w2g = W2t + (size_t)n2a * 1024 + phs * 512;                   // + c*16

  // b1 -> LDS (1024 f32)
  ((vf4*)b1s)[tid] = ((const vf4*)b1)[tid];

  vs8 r1[4]; vh8 r2a[2], r2b[2];
  const vh4* r2a4 = (const vh4*)r2a;   // 4 contiguous vh4 views
  const vh4* r2b4 = (const vh4*)r2b;
  // stage chunk 0 into buf 0
#pragma unroll
  for (int i = 0; i < 4; ++i) r1[i] = *(const vs8*)(w1g + i * 8);
  r2a[0] = *(const vh8*)(w2g);        r2a[1] = *(const vh8*)(w2g + 8);
  r2b[0] = *(const vh8*)(w2g + 1024); r2b[1] = *(const vh8*)(w2g + 1032);
  {
    u16* d1 = lds + phs * 4096 + (w1seg * 64 + w1row) * 8;
#pragma unroll
    for (int i = 0; i < 4; ++i) *(vs8*)(d1 + i * 128) = r1[i];
    f16* base = (f16*)lds + 8192 + phs * 4096;
    f16* da = base + ((n2a >> 4) * 64 + (n2a & 15)) * 4;
    f16* db = base + ((n2b >> 4) * 64 + (n2b & 15)) * 4;
#pragma unroll
    for (int q = 0; q < 4; ++q) {
      *(vh4*)(da + q * 64) = r2a4[q];
      *(vh4*)(db + q * 64) = r2b4[q];
    }
  }
  __syncthreads();

  const vf4 z4 = {0.f, 0.f, 0.f, 0.f};

  for (int c = 0; c < 32; ++c) {
    int cur = c & 1;
    if (c < 31) {   // prefetch chunk c+1 into regs (in flight during compute)
      const u16* g1 = w1g + (size_t)(c + 1) * 16 * 256;
#pragma unroll
      for (int i = 0; i < 4; ++i) r1[i] = *(const vs8*)(g1 + i * 8);
      const f16* g2 = w2g + (c + 1) * 16;
      r2a[0] = *(const vh8*)(g2);        r2a[1] = *(const vh8*)(g2 + 8);
      r2b[0] = *(const vh8*)(g2 + 1024); r2b[1] = *(const vh8*)(g2 + 1032);
    }

    // ff1: C1^T tile (16 n1 x 16 m), K=256 — lane-linear b128 reads
    const u16* w1p = lds + cur * 16384 + ph * 4096;
    vf4 acc1 = z4;
#pragma unroll
    for (int s = 0; s < 8; ++s) {
      vs8 a = *(const vs8*)(w1p + (s * 64 + lane) * 8);
      acc1 = __builtin_amdgcn_mfma_f32_16x16x32_bf16(a, xv[s], acc1, 0, 0, 0);
    }
    // bias + relu + pack f16 (A-frag of 16x16x16: m=lane&15, k=quad*4+j == n1-local)
    int n1b = ph * 512 + c * 16 + quad * 4;
    float t0 = fmaxf(acc1[0] + b1s[n1b + 0], 0.f);
    float t1 = fmaxf(acc1[1] + b1s[n1b + 1], 0.f);
    float t2 = fmaxf(acc1[2] + b1s[n1b + 2], 0.f);
    float t3 = fmaxf(acc1[3] + b1s[n1b + 3], 0.f);
    vh4 p;
    ((hw2*)&p)[0] = __builtin_amdgcn_cvt_pkrtz(t0, t1);
    ((hw2*)&p)[1] = __builtin_amdgcn_cvt_pkrtz(t2, t3);
    // ff2: 16 n2-tiles — lane-linear b64 reads
    const f16* w2p = (const f16*)lds + cur * 16384 + 8192 + ph * 4096;
#pragma unroll
    for (int nt = 0; nt < 16; ++nt) {
      vh4 bf = *(const vh4*)(w2p + (nt * 64 + lane) * 4);
      acc2[nt] = __builtin_amdgcn_mfma_f32_16x16x16f16(p, bf, acc2[nt], 0, 0, 0);
    }

    if (c < 31) {   // write prefetched chunk into the other buffer
      int nb = cur ^ 1;
      u16* d1 = lds + nb * 16384 + phs * 4096 + (w1seg * 64 + w1row) * 8;
#pragma unroll
      for (int i = 0; i < 4; ++i) *(vs8*)(d1 + i * 128) = r1[i];
      f16* base = (f16*)lds + nb * 16384 + 8192 + phs * 4096;
      f16* da = base + ((n2a >> 4) * 64 + (n2a & 15)) * 4;
      f16* db = base + ((n2b >> 4) * 64 + (n2b & 15)) * 4;
#pragma unroll
      for (int q = 0; q < 4; ++q) {
        *(vh4*)(da + q * 64) = r2a4[q];
        *(vh4*)(db + q * 64) = r2b4[q];
      }
    }
    __syncthreads();
  }

  // merge ph=1 partials into ph=0 via LDS (f32 [2][16][257] overlay)
  if (ph == 1) {
#pragma unroll
    for (int nt = 0; nt < 16; ++nt)
#pragma unroll
      for (int r = 0; r < 4; ++r)
        mergef[(mh * 16 + quad * 4 + r) * 257 + nt * 16 + lr] = acc2[nt][r];
  }
  __syncthreads();
  if (ph == 0) {
    const __hip_bfloat16* resb = (const __hip_bfloat16*)Xb;
    float b2v[16], gv[16], bv_[16];
#pragma unroll
    for (int nt = 0; nt < 16; ++nt) {
      int col = nt * 16 + lr;
      b2v[nt] = b2[col]; gv[nt] = gam[col]; bv_[nt] = bet[col];
    }
#pragma unroll
    for (int r = 0; r < 4; ++r) {
      int gr = m0 + mh * 16 + quad * 4 + r;
      float v[16], sum = 0.f, sq = 0.f;
#pragma unroll
      for (int nt = 0; nt < 16; ++nt) {
        int col = nt * 16 + lr;
        float x = acc2[nt][r] + mergef[(mh * 16 + quad * 4 + r) * 257 + col]
                + b2v[nt] + __bfloat162float(resb[(size_t)gr * 256 + col]);
        v[nt] = x; sum += x; sq += x * x;
      }
#pragma unroll
      for (int m = 1; m <= 8; m <<= 1) {
        sum += __shfl_xor(sum, m);
        sq  += __shfl_xor(sq, m);
      }
      float mu = sum * (1.0f / 256.0f);
      float var = sq * (1.0f / 256.0f) - mu * mu;
      float rs = rsqrtf(var + 1e-5f);
#pragma unroll
      for (int nt = 0; nt < 16; ++nt) {
        int col = nt * 16 + lr;
        float o = (v[nt] - mu) * rs * gv[nt] + bv_[nt];
        outB[(size_t)gr * 256 + col] = __float2bfloat16(o);
        if (outF) outF[(size_t)gr * 256 + col] = o;
      }
    }
  }
}

// ---------------- MFMA flash attention (unchanged from R7) ----------------
__global__ __launch_bounds__(512, 4) void attn_mfma(const f16* __restrict__ qkv,
                                                    __hip_bfloat16* __restrict__ out) {
  __shared__ __align__(16) u16 lds[2][4736];
  int tid = threadIdx.x;
  int wave = tid >> 6, lane = tid & 63;
  int lr = lane & 15, quad = lane >> 4;

  int id = blockIdx.x;
  int xcd = id & 7, slot = id >> 3;
  int grp = xcd * 4 + (slot & 3);
  int qt = slot >> 2;
  int b = grp >> 3, h = grp & 7;
  int q0 = qt * 256;
  int rowbase = b * 2048;
  const f16* base_bh = qkv + (size_t)rowbase * 768 + h * 96;

  vh8 qf[2];
#pragma unroll
  for (int nt = 0; nt < 2; ++nt) {
    int qr = q0 + wave * 32 + nt * 16 + lr;
    vh8 t = *(const vh8*)(base_bh + (size_t)qr * 768 + quad * 8);
#pragma unroll
    for (int j = 0; j < 8; ++j) t[j] = t[j] * (f16)0.25508682f;
    qf[nt] = t;
  }

  vf4 O[2][2], lO[2];
#pragma unroll
  for (int a = 0; a < 2; ++a) {
    lO[a][0]=0.f; lO[a][1]=0.f; lO[a][2]=0.f; lO[a][3]=0.f;
#pragma unroll
    for (int d = 0; d < 2; ++d) { O[a][d][0]=0.f; O[a][d][1]=0.f; O[a][d][2]=0.f; O[a][d][3]=0.f; }
  }

  int krow = wave * 16 + (lane >> 2);
  int kcol = (lane & 3) * 8;
  const f16* kg = base_bh + (size_t)krow * 768 + 32 + kcol;
  int tv = tid & 255;
  int kvp = tv >> 3;
  int d4 = (tv & 7) * 4;
  const f16* vg = base_bh + (size_t)(kvp * 2) * 768 + 64 + d4;

  const vf4 z4 = {0.f, 0.f, 0.f, 0.f};
  const vh4 onesh = {(f16)1.0f, (f16)1.0f, (f16)1.0f, (f16)1.0f};
  const size_t cstep = (size_t)64 * 768;

  if (wave < 4) {
    vh8 k0 = *(const vh8*)kg;
    *(vh8*)&lds[0][krow * 40 + kcol] = k0;
  } else {
    vh4 a = *(const vh4*)vg;
    vh4 bb = *(const vh4*)(vg + 768);
#pragma unroll
    for (int i = 0; i < 4; ++i) {
      vh2 pr; pr[0] = a[i]; pr[1] = bb[i];
      *(vh2*)((f16*)&lds[0][2560] + (d4 + i) * 68 + kvp * 2) = pr;
    }
  }
  __syncthreads();

  for (int c = 0; c < 32; ++c) {
    int cur = c & 1;
    const f16* Ks = (const f16*)&lds[cur][0];
    const f16* VT = (const f16*)&lds[cur][2560];

    vh8 kn; vh4 va, vb;
    if (c < 31) {
      if (wave < 4) {
        kn = *(const vh8*)(kg + (size_t)(c + 1) * cstep);
      } else {
        const f16* vp = vg + (size_t)(c + 1) * cstep;
        va = *(const vh4*)vp;
        vb = *(const vh4*)(vp + 768);
      }
    }

#pragma unroll
    for (int t16 = 0; t16 < 4; ++t16) {
      vh8 ak = *(const vh8*)&Ks[(t16 * 16 + lr) * 40 + quad * 8];
      vf4 s0 = __builtin_amdgcn_mfma_f32_16x16x32_f16(ak, qf[0], z4, 0, 0, 0);
      vf4 s1 = __builtin_amdgcn_mfma_f32_16x16x32_f16(ak, qf[1], z4, 0, 0, 0);
      vh4 p0, p1;
      ((hw2*)&p0)[0] = __builtin_amdgcn_cvt_pkrtz(fexp2(s0[0]), fexp2(s0[1]));
      ((hw2*)&p0)[1] = __builtin_amdgcn_cvt_pkrtz(fexp2(s0[2]), fexp2(s0[3]));
      ((hw2*)&p1)[0] = __builtin_amdgcn_cvt_pkrtz(fexp2(s1[0]), fexp2(s1[1]));
      ((hw2*)&p1)[1] = __builtin_amdgcn_cvt_pkrtz(fexp2(s1[2]), fexp2(s1[3]));
      vh4 vf0 = *(const vh4*)&VT[(0 * 16 + lr) * 68 + t16 * 16 + quad * 4];
      vh4 vf1 = *(const vh4*)&VT[(1 * 16 + lr) * 68 + t16 * 16 + quad * 4];
      O[0][0] = __builtin_amdgcn_mfma_f32_16x16x16f16(p0, vf0, O[0][0], 0, 0, 0);
      O[0][1] = __builtin_amdgcn_mfma_f32_16x16x16f16(p0, vf1, O[0][1], 0, 0, 0);
      O[1][0] = __builtin_amdgcn_mfma_f32_16x16x16f16(p1, vf0, O[1][0], 0, 0, 0);
      O[1][1] = __builtin_amdgcn_mfma_f32_16x16x16f16(p1, vf1, O[1][1], 0, 0, 0);
      lO[0] = __builtin_amdgcn_mfma_f32_16x16x16f16(p0, onesh, lO[0], 0, 0, 0);
      lO[1] = __builtin_amdgcn_mfma_f32_16x16x16f16(p1, onesh, lO[1], 0, 0, 0);
    }

    if (c < 31) {
      if (wave < 4) {
        *(vh8*)&lds[cur ^ 1][krow * 40 + kcol] = kn;
      } else {
#pragma unroll
        for (int i = 0; i < 4; ++i) {
          vh2 pr; pr[0] = va[i]; pr[1] = vb[i];
          *(vh2*)((f16*)&lds[cur ^ 1][2560] + (d4 + i) * 68 + kvp * 2) = pr;
        }
      }
    }
    __syncthreads();
  }

#pragma unroll
  for (int nt = 0; nt < 2; ++nt) {
#pragma unroll
    for (int r = 0; r < 4; ++r) {
      float inv = 1.0f / lO[nt][r];
      int row = rowbase + q0 + wave * 32 + nt * 16 + quad * 4 + r;
#pragma unroll
      for (int dt = 0; dt < 2; ++dt) {
        int col = h * 32 + dt * 16 + lr;
        out[(size_t)row * 256 + col] = __float2bfloat16(O[nt][dt][r] * inv);
      }
    }
  }
}

// ---------------- driver ----------------
extern "C" void kernel_launch(void* const* d_in, const int* in_sizes, int n_in,
                              void* d_out, int out_size, void* d_ws, size_t ws_size,
                              hipStream_t stream) {
  (void)in_sizes; (void)n_in; (void)out_size; (void)ws_size;
  const float* x     = (const float*)d_in[0];
  const float* qkv_b = (const float*)d_in[2];
  const float* out_b = (const float*)d_in[4];
  const float* ff1_b = (const float*)d_in[6];
  const float* ff2_b = (const float*)d_in[8];
  const float* ln1_g = (const float*)d_in[9];
  const float* ln1_b = (const float*)d_in[10];
  const float* ln2_g = (const float*)d_in[11];
  const float* ln2_b = (const float*)d_in[12];

  // ws layout (bytes); total = 44,040,192
  char* ws = (char*)d_ws;
  __hip_bfloat16* Xb    = (__hip_bfloat16*)(ws + 8388608);     // bf16 x (carried state)
  __hip_bfloat16* attnB = (__hip_bfloat16*)(ws + 20971520);    // attn out bf16 (4 MB)
  f16*            qkvH  = (f16*)(ws + 25165824);               // 8192x768 f16 (12.6 MB)
  u16* qkvwT = (u16*)(ws + 37748736);  // [L][768][256] bf16
  u16* outwT = (u16*)(ws + 39321600);  // [L][256][256] bf16
  u16* ff1wT = (u16*)(ws + 39845888);  // [L][1024][256] bf16
  u16* ff2wH = (u16*)(ws + 41943040);  // [L][256][1024] f16  ends 44,040,192

  pe_kernel<<<8192, 256, 0, stream>>>(x, Xb);
  transpose_cast<<<dim3(8, 24, 4), dim3(32, 8), 0, stream>>>((const float*)d_in[1], qkvwT, 256, 768, 0);
  transpose_cast<<<dim3(8, 8, 4),  dim3(32, 8), 0, stream>>>((const float*)d_in[3], outwT, 256, 256, 0);
  transpose_cast<<<dim3(8, 32, 4), dim3(32, 8), 0, stream>>>((const float*)d_in[5], ff1wT, 256, 1024, 0);
  transpose_cast<<<dim3(32, 8, 4), dim3(32, 8), 0, stream>>>((const float*)d_in[7], ff2wH, 1024, 256, 1);

  for (int l = 0; l < 4; ++l) {
    // qkv = x @ qkv_w + b -> f16
    gemm_qkv<<<dim3(6, 128), 256, 0, stream>>>((const u16*)Xb, qkvwT + (size_t)l * 768 * 256,
        qkv_b + l * 768, qkvH, 8192, 768, 256);
    // attn
    attn_mfma<<<256, 512, 0, stream>>>(qkvH, attnB);
    // Xb = LN1(attn @ out_w + b + Xb)
    gemm_ln<<<256, 256, 0, stream>>>((const u16*)attnB, outwT + (size_t)l * 256 * 256,
        out_b + l * 256, Xb, ln1_g + l * 256, ln1_b + l * 256, Xb, 256);
    // Xb = LN2(relu(Xb@W1+b1)@W2 + b2 + Xb); last layer also writes d_out f32
    float* lnout = (l == 3) ? (float*)d_out : nullptr;
    ffn_fused<<<256, 256, 0, stream>>>((const u16*)Xb, ff1wT + (size_t)l * 1024 * 256,
        ff1_b + l * 1024, (const f16*)(ff2wH + (size_t)l * 256 * 1024), ff2_b + l * 256,
        ln2_g + l * 256, ln2_b + l * 256, Xb, lnout);
  }
}

// Round 12
// 473.042 us; speedup vs baseline: 1.1834x; 1.1834x over previous
//
#include <hip/hip_runtime.h>
#include <hip/hip_bf16.h>
#include <stdint.h>

typedef unsigned short u16;
typedef _Float16 f16;
typedef short vs8 __attribute__((ext_vector_type(8)));   // 8 x bf16 bits (MFMA A/B frag)
typedef float vf4 __attribute__((ext_vector_type(4)));   // MFMA C/D frag
typedef _Float16 vh2 __attribute__((ext_vector_type(2)));
typedef _Float16 vh4 __attribute__((ext_vector_type(4)));
typedef _Float16 vh8 __attribute__((ext_vector_type(8)));
typedef __fp16 hw2 __attribute__((ext_vector_type(2)));  // cvt_pkrtz return type

// Problem constants: B=4 T=2048 E=256 H=8 HD=32 FE=4 L=4

__device__ __forceinline__ void gload16(const u16* g, u16* l) {
  __builtin_amdgcn_global_load_lds((const __attribute__((address_space(1))) void*)g,
                                   (__attribute__((address_space(3))) void*)l,
                                   16, 0, 0);
}

__device__ __forceinline__ float fexp2(float x) {
#if __has_builtin(__builtin_amdgcn_exp2f)
  return __builtin_amdgcn_exp2f(x);
#else
  return __expf(x * 0.69314718056f);
#endif
}

// ---------------- Fourier PE -> bf16 only ----------------
__global__ void pe_kernel(const float* __restrict__ x, __hip_bfloat16* __restrict__ Xb) {
  int row = blockIdx.x;            // b*2048 + t
  int e = threadIdx.x;             // 0..255
  int t = row & 2047;
  int f = (e < 128) ? e : (e - 128);
  float freq = powf(10000.0f, -(float)f * (1.0f / 128.0f));
  float arg = (float)t * freq;
  float pe = (e < 128) ? sinf(arg) : cosf(arg);
  size_t idx = (size_t)row * 256 + e;
  Xb[idx] = __float2bfloat16(x[idx] + pe);
}

// ---------------- weight transpose + cast: in[L][K][N] f32 -> out[L][N][K] bf16 ----------------
__global__ void transpose_cast(const float* __restrict__ in, u16* __restrict__ out,
                               int K, int N) {
  __shared__ float tile[32][33];
  int layer = blockIdx.z;
  int k0 = blockIdx.x * 32, n0 = blockIdx.y * 32;
  const float* ip = in + (size_t)layer * K * N;
  u16* op = out + (size_t)layer * N * K;
  int tx = threadIdx.x, ty = threadIdx.y;   // (32,8)
#pragma unroll
  for (int r = 0; r < 4; ++r) {
    int k = ty + r * 8;
    tile[k][tx] = ip[(size_t)(k0 + k) * N + (n0 + tx)];
  }
  __syncthreads();
#pragma unroll
  for (int r = 0; r < 4; ++r) {
    int n = ty + r * 8;
    __hip_bfloat16 v = __float2bfloat16(tile[tx][n]);
    op[(size_t)(n0 + n) * K + (k0 + tx)] = *(u16*)&v;
  }
}

// ---------------- bf16 MFMA GEMM 128x128 (ff1): C = relu(A@W + bias) -> bf16 ----------------
// m97-lineage proven structure. Grid (N/128, M/128) = (8,64) = 512 blocks -> 2 blocks/CU.
__global__ __launch_bounds__(256, 2) void gemm_relu(
    const u16* __restrict__ A, const u16* __restrict__ Bt,
    const float* __restrict__ bias, __hip_bfloat16* __restrict__ outB,
    int M, int N, int K) {
  __shared__ u16 As[128 * 32];
  __shared__ u16 Bs[128 * 32];
  int tid = threadIdx.x;
  int wave = tid >> 6, lane = tid & 63;
  int wm = wave & 1, wn = wave >> 1;              // 2x2 waves of 64x64
  int m0 = blockIdx.y * 128, n0 = blockIdx.x * 128;
  int lr = lane & 15, lq = lane >> 4;

  vf4 acc[4][4];
#pragma unroll
  for (int i = 0; i < 4; ++i)
#pragma unroll
    for (int j = 0; j < 4; ++j) {
      acc[i][j][0] = 0.f; acc[i][j][1] = 0.f; acc[i][j][2] = 0.f; acc[i][j][3] = 0.f;
    }

  int srow = wave * 16 + (lane >> 2);
  int scol = (lane & 3) * 8;
  const u16* ag = A + (size_t)(m0 + srow) * K + scol;
  const u16* bg = Bt + (size_t)(n0 + srow) * K + scol;
  u16* al = As + srow * 32 + scol;
  u16* bl = Bs + srow * 32 + scol;
  const size_t rstride = (size_t)64 * K;

  for (int k0 = 0; k0 < K; k0 += 32) {
    gload16(ag + k0, al);
    gload16(ag + k0 + rstride, al + 64 * 32);
    gload16(bg + k0, bl);
    gload16(bg + k0 + rstride, bl + 64 * 32);
    __syncthreads();
    vs8 av[4], bv[4];
#pragma unroll
    for (int i = 0; i < 4; ++i)
      av[i] = *(const vs8*)&As[(wm * 64 + i * 16 + lr) * 32 + lq * 8];
#pragma unroll
    for (int j = 0; j < 4; ++j)
      bv[j] = *(const vs8*)&Bs[(wn * 64 + j * 16 + lr) * 32 + lq * 8];
#pragma unroll
    for (int i = 0; i < 4; ++i)
#pragma unroll
      for (int j = 0; j < 4; ++j)
        acc[i][j] = __builtin_amdgcn_mfma_f32_16x16x32_bf16(av[i], bv[j], acc[i][j], 0, 0, 0);
    __syncthreads();
  }

#pragma unroll
  for (int i = 0; i < 4; ++i) {
    int row0 = m0 + wm * 64 + i * 16 + lq * 4;
#pragma unroll
    for (int j = 0; j < 4; ++j) {
      int col = n0 + wn * 64 + j * 16 + lr;
      float bb = bias[col];
#pragma unroll
      for (int r = 0; r < 4; ++r) {
        size_t idx = (size_t)(row0 + r) * N + col;
        outB[idx] = __float2bfloat16(fmaxf(acc[i][j][r] + bb, 0.0f));
      }
    }
  }
}

// ---------------- bf16 MFMA GEMM 64x128 (qkv): C = A@W + bias -> f16 ----------------
__global__ __launch_bounds__(256, 2) void gemm_qkv(
    const u16* __restrict__ A, const u16* __restrict__ Bt,
    const float* __restrict__ bias, f16* __restrict__ outH,
    int M, int N, int K) {
  __shared__ u16 As[64 * 32];
  __shared__ u16 Bs[128 * 32];
  int tid = threadIdx.x;
  int wave = tid >> 6, lane = tid & 63;
  int wm = wave & 1, wn = wave >> 1;              // wave = 32 rows x 64 cols
  int m0 = blockIdx.y * 64, n0 = blockIdx.x * 128;
  int lr = lane & 15, lq = lane >> 4;

  vf4 acc[2][4];
#pragma unroll
  for (int i = 0; i < 2; ++i)
#pragma unroll
    for (int j = 0; j < 4; ++j) { acc[i][j][0]=0.f; acc[i][j][1]=0.f; acc[i][j][2]=0.f; acc[i][j][3]=0.f; }

  int sr = tid >> 2, sc = (tid & 3) * 8;
  const u16* ag = A + (size_t)(m0 + sr) * K + sc;
  const u16* bg = Bt + (size_t)(n0 + sr) * K + sc;
  u16* al = As + sr * 32 + sc;
  u16* bl = Bs + sr * 32 + sc;

  for (int k0 = 0; k0 < K; k0 += 32) {
    gload16(ag + k0, al);
    gload16(bg + k0, bl);
    gload16(bg + k0 + (size_t)64 * K, bl + 64 * 32);
    __syncthreads();
    vs8 av[2], bv[4];
#pragma unroll
    for (int i = 0; i < 2; ++i)
      av[i] = *(const vs8*)&As[(wm * 32 + i * 16 + lr) * 32 + lq * 8];
#pragma unroll
    for (int j = 0; j < 4; ++j)
      bv[j] = *(const vs8*)&Bs[(wn * 64 + j * 16 + lr) * 32 + lq * 8];
#pragma unroll
    for (int i = 0; i < 2; ++i)
#pragma unroll
      for (int j = 0; j < 4; ++j)
        acc[i][j] = __builtin_amdgcn_mfma_f32_16x16x32_bf16(av[i], bv[j], acc[i][j], 0, 0, 0);
    __syncthreads();
  }

#pragma unroll
  for (int i = 0; i < 2; ++i) {
    int row0 = m0 + wm * 32 + i * 16 + lq * 4;
#pragma unroll
    for (int j = 0; j < 4; ++j) {
      int col = n0 + wn * 64 + j * 16 + lr;
      float bb = bias[col];
#pragma unroll
      for (int r = 0; r < 4; ++r)
        outH[(size_t)(row0 + r) * N + col] = (f16)(acc[i][j][r] + bb);
    }
  }
}

// ---------------- fused GEMM (N=256) + bias + bf16 residual + LN -> bf16 (+f32 opt) ----------------
// v2: 512 threads = 8 waves (wm 2 x wn 4); wave = 16 rows x 64 cols. Grid 256, 8 waves/CU
// (R9-R11 post-mortem: 4 waves/CU was the FFN/LN bottleneck — latency with no TLP).
__global__ __launch_bounds__(512, 2) void gemm_ln(
    const u16* __restrict__ A, const u16* __restrict__ Bt,
    const float* __restrict__ bias, const __hip_bfloat16* __restrict__ res,
    const float* __restrict__ gam, const float* __restrict__ bet,
    __hip_bfloat16* __restrict__ outB, float* __restrict__ outF, int K) {
  __shared__ u16 As[32 * 32];
  __shared__ u16 Bs[256 * 32];
  __shared__ float ps[4][32], ps2[4][32], mur[32], rsr[32];
  int tid = threadIdx.x;
  int wave = tid >> 6, lane = tid & 63;
  int wm = wave & 1, wn = wave >> 1;              // wn 0..3
  int lr = lane & 15, lq = lane >> 4;
  int m0 = blockIdx.x * 32;

  vf4 acc[4];
#pragma unroll
  for (int j = 0; j < 4; ++j) { acc[j][0]=0.f; acc[j][1]=0.f; acc[j][2]=0.f; acc[j][3]=0.f; }

  int sr = tid >> 2, sc = (tid & 3) * 8;          // sr 0..127
  const u16* ag = A + (size_t)(m0 + sr) * K + sc; // deref only for tid<128 (rows 0..31)
  const u16* bg = Bt + (size_t)sr * K + sc;       // rows 0..127; +128 for round 2
  u16* al = As + sr * 32 + sc;
  u16* bl = Bs + sr * 32 + sc;

  for (int k0 = 0; k0 < K; k0 += 32) {
    if (tid < 128) gload16(ag + k0, al);
    gload16(bg + k0, bl);
    gload16(bg + k0 + (size_t)128 * K, bl + 128 * 32);
    __syncthreads();
    vs8 av, bv[4];
    av = *(const vs8*)&As[(wm * 16 + lr) * 32 + lq * 8];
#pragma unroll
    for (int j = 0; j < 4; ++j)
      bv[j] = *(const vs8*)&Bs[(wn * 64 + j * 16 + lr) * 32 + lq * 8];
#pragma unroll
    for (int j = 0; j < 4; ++j)
      acc[j] = __builtin_amdgcn_mfma_f32_16x16x32_bf16(av, bv[j], acc[j], 0, 0, 0);
    __syncthreads();
  }

  // v = acc + bias + residual; per-row partial sums over this wave's 64 cols
  float sum_[4], sq_[4];
#pragma unroll
  for (int r = 0; r < 4; ++r) { sum_[r] = 0.f; sq_[r] = 0.f; }
#pragma unroll
  for (int j = 0; j < 4; ++j) {
    int col = wn * 64 + j * 16 + lr;
    float bb = bias[col];
#pragma unroll
    for (int r = 0; r < 4; ++r) {
      int row = m0 + wm * 16 + lq * 4 + r;
      float v = acc[j][r] + bb + __bfloat162float(res[(size_t)row * 256 + col]);
      acc[j][r] = v;
      sum_[r] += v;
      sq_[r] += v * v;
    }
  }
#pragma unroll
  for (int r = 0; r < 4; ++r) {
#pragma unroll
    for (int m = 1; m <= 8; m <<= 1) {
      sum_[r] += __shfl_xor(sum_[r], m);
      sq_[r]  += __shfl_xor(sq_[r], m);
    }
  }
  if (lr == 0) {
#pragma unroll
    for (int r = 0; r < 4; ++r) {
      int rl = wm * 16 + lq * 4 + r;     // 0..31, disjoint across wm
      ps[wn][rl] = sum_[r];
      ps2[wn][rl] = sq_[r];
    }
  }
  __syncthreads();
  if (tid < 32) {
    float s = ps[0][tid] + ps[1][tid] + ps[2][tid] + ps[3][tid];
    float s2 = ps2[0][tid] + ps2[1][tid] + ps2[2][tid] + ps2[3][tid];
    float mu = s * (1.0f / 256.0f);
    float var = s2 * (1.0f / 256.0f) - mu * mu;
    mur[tid] = mu;
    rsr[tid] = rsqrtf(var + 1e-5f);
  }
  __syncthreads();
#pragma unroll
  for (int r = 0; r < 4; ++r) {
    int rl = wm * 16 + lq * 4 + r;
    float mu = mur[rl], rs = rsr[rl];
    int row = m0 + rl;
#pragma unroll
    for (int j = 0; j < 4; ++j) {
      int col = wn * 64 + j * 16 + lr;
      float o = (acc[j][r] - mu) * rs * gam[col] + bet[col];
      size_t idx = (size_t)row * 256 + col;
      outB[idx] = __float2bfloat16(o);
      if (outF) outF[idx] = o;
    }
  }
}

// ---------------- MFMA flash attention (unchanged from R7) ----------------
__global__ __launch_bounds__(512, 4) void attn_mfma(const f16* __restrict__ qkv,
                                                    __hip_bfloat16* __restrict__ out) {
  __shared__ __align__(16) u16 lds[2][4736];
  int tid = threadIdx.x;
  int wave = tid >> 6, lane = tid & 63;
  int lr = lane & 15, quad = lane >> 4;

  int id = blockIdx.x;
  int xcd = id & 7, slot = id >> 3;
  int grp = xcd * 4 + (slot & 3);
  int qt = slot >> 2;
  int b = grp >> 3, h = grp & 7;
  int q0 = qt * 256;
  int rowbase = b * 2048;
  const f16* base_bh = qkv + (size_t)rowbase * 768 + h * 96;

  vh8 qf[2];
#pragma unroll
  for (int nt = 0; nt < 2; ++nt) {
    int qr = q0 + wave * 32 + nt * 16 + lr;
    vh8 t = *(const vh8*)(base_bh + (size_t)qr * 768 + quad * 8);
#pragma unroll
    for (int j = 0; j < 8; ++j) t[j] = t[j] * (f16)0.25508682f;
    qf[nt] = t;
  }

  vf4 O[2][2], lO[2];
#pragma unroll
  for (int a = 0; a < 2; ++a) {
    lO[a][0]=0.f; lO[a][1]=0.f; lO[a][2]=0.f; lO[a][3]=0.f;
#pragma unroll
    for (int d = 0; d < 2; ++d) { O[a][d][0]=0.f; O[a][d][1]=0.f; O[a][d][2]=0.f; O[a][d][3]=0.f; }
  }

  int krow = wave * 16 + (lane >> 2);
  int kcol = (lane & 3) * 8;
  const f16* kg = base_bh + (size_t)krow * 768 + 32 + kcol;
  int tv = tid & 255;
  int kvp = tv >> 3;
  int d4 = (tv & 7) * 4;
  const f16* vg = base_bh + (size_t)(kvp * 2) * 768 + 64 + d4;

  const vf4 z4 = {0.f, 0.f, 0.f, 0.f};
  const vh4 onesh = {(f16)1.0f, (f16)1.0f, (f16)1.0f, (f16)1.0f};
  const size_t cstep = (size_t)64 * 768;

  if (wave < 4) {
    vh8 k0 = *(const vh8*)kg;
    *(vh8*)&lds[0][krow * 40 + kcol] = k0;
  } else {
    vh4 a = *(const vh4*)vg;
    vh4 bb = *(const vh4*)(vg + 768);
#pragma unroll
    for (int i = 0; i < 4; ++i) {
      vh2 pr; pr[0] = a[i]; pr[1] = bb[i];
      *(vh2*)((f16*)&lds[0][2560] + (d4 + i) * 68 + kvp * 2) = pr;
    }
  }
  __syncthreads();

  for (int c = 0; c < 32; ++c) {
    int cur = c & 1;
    const f16* Ks = (const f16*)&lds[cur][0];
    const f16* VT = (const f16*)&lds[cur][2560];

    vh8 kn; vh4 va, vb;
    if (c < 31) {
      if (wave < 4) {
        kn = *(const vh8*)(kg + (size_t)(c + 1) * cstep);
      } else {
        const f16* vp = vg + (size_t)(c + 1) * cstep;
        va = *(const vh4*)vp;
        vb = *(const vh4*)(vp + 768);
      }
    }

#pragma unroll
    for (int t16 = 0; t16 < 4; ++t16) {
      vh8 ak = *(const vh8*)&Ks[(t16 * 16 + lr) * 40 + quad * 8];
      vf4 s0 = __builtin_amdgcn_mfma_f32_16x16x32_f16(ak, qf[0], z4, 0, 0, 0);
      vf4 s1 = __builtin_amdgcn_mfma_f32_16x16x32_f16(ak, qf[1], z4, 0, 0, 0);
      vh4 p0, p1;
      ((hw2*)&p0)[0] = __builtin_amdgcn_cvt_pkrtz(fexp2(s0[0]), fexp2(s0[1]));
      ((hw2*)&p0)[1] = __builtin_amdgcn_cvt_pkrtz(fexp2(s0[2]), fexp2(s0[3]));
      ((hw2*)&p1)[0] = __builtin_amdgcn_cvt_pkrtz(fexp2(s1[0]), fexp2(s1[1]));
      ((hw2*)&p1)[1] = __builtin_amdgcn_cvt_pkrtz(fexp2(s1[2]), fexp2(s1[3]));
      vh4 vf0 = *(const vh4*)&VT[(0 * 16 + lr) * 68 + t16 * 16 + quad * 4];
      vh4 vf1 = *(const vh4*)&VT[(1 * 16 + lr) * 68 + t16 * 16 + quad * 4];
      O[0][0] = __builtin_amdgcn_mfma_f32_16x16x16f16(p0, vf0, O[0][0], 0, 0, 0);
      O[0][1] = __builtin_amdgcn_mfma_f32_16x16x16f16(p0, vf1, O[0][1], 0, 0, 0);
      O[1][0] = __builtin_amdgcn_mfma_f32_16x16x16f16(p1, vf0, O[1][0], 0, 0, 0);
      O[1][1] = __builtin_amdgcn_mfma_f32_16x16x16f16(p1, vf1, O[1][1], 0, 0, 0);
      lO[0] = __builtin_amdgcn_mfma_f32_16x16x16f16(p0, onesh, lO[0], 0, 0, 0);
      lO[1] = __builtin_amdgcn_mfma_f32_16x16x16f16(p1, onesh, lO[1], 0, 0, 0);
    }

    if (c < 31) {
      if (wave < 4) {
        *(vh8*)&lds[cur ^ 1][krow * 40 + kcol] = kn;
      } else {
#pragma unroll
        for (int i = 0; i < 4; ++i) {
          vh2 pr; pr[0] = va[i]; pr[1] = vb[i];
          *(vh2*)((f16*)&lds[cur ^ 1][2560] + (d4 + i) * 68 + kvp * 2) = pr;
        }
      }
    }
    __syncthreads();
  }

#pragma unroll
  for (int nt = 0; nt < 2; ++nt) {
#pragma unroll
    for (int r = 0; r < 4; ++r) {
      float inv = 1.0f / lO[nt][r];
      int row = rowbase + q0 + wave * 32 + nt * 16 + quad * 4 + r;
#pragma unroll
      for (int dt = 0; dt < 2; ++dt) {
        int col = h * 32 + dt * 16 + lr;
        out[(size_t)row * 256 + col] = __float2bfloat16(O[nt][dt][r] * inv);
      }
    }
  }
}

// ---------------- driver ----------------
extern "C" void kernel_launch(void* const* d_in, const int* in_sizes, int n_in,
                              void* d_out, int out_size, void* d_ws, size_t ws_size,
                              hipStream_t stream) {
  (void)in_sizes; (void)n_in; (void)out_size; (void)ws_size;
  const float* x     = (const float*)d_in[0];
  const float* qkv_b = (const float*)d_in[2];
  const float* out_b = (const float*)d_in[4];
  const float* ff1_b = (const float*)d_in[6];
  const float* ff2_b = (const float*)d_in[8];
  const float* ln1_g = (const float*)d_in[9];
  const float* ln1_b = (const float*)d_in[10];
  const float* ln2_g = (const float*)d_in[11];
  const float* ln2_b = (const float*)d_in[12];

  // ws layout (bytes); total = 44,040,192
  char* ws = (char*)d_ws;
  __hip_bfloat16* Xb    = (__hip_bfloat16*)(ws + 8388608);     // bf16 x (carried state, 4 MB)
  __hip_bfloat16* attnB = (__hip_bfloat16*)(ws + 20971520);    // attn out bf16 (4 MB)
  f16*            qkvH  = (f16*)(ws + 25165824);               // 8192x768 f16 (12.6 MB)
  __hip_bfloat16* hB    = (__hip_bfloat16*)(ws + 20971520);    // ff1 out bf16 (16.8 MB) overlaps attnB+qkvH (both dead by ff1)
  u16* qkvwT = (u16*)(ws + 37748736);  // [L][768][256] bf16
  u16* outwT = (u16*)(ws + 39321600);  // [L][256][256] bf16
  u16* ff1wT = (u16*)(ws + 39845888);  // [L][1024][256] bf16
  u16* ff2wT = (u16*)(ws + 41943040);  // [L][256][1024] bf16  ends 44,040,192

  pe_kernel<<<8192, 256, 0, stream>>>(x, Xb);
  transpose_cast<<<dim3(8, 24, 4), dim3(32, 8), 0, stream>>>((const float*)d_in[1], qkvwT, 256, 768);
  transpose_cast<<<dim3(8, 8, 4),  dim3(32, 8), 0, stream>>>((const float*)d_in[3], outwT, 256, 256);
  transpose_cast<<<dim3(8, 32, 4), dim3(32, 8), 0, stream>>>((const float*)d_in[5], ff1wT, 256, 1024);
  transpose_cast<<<dim3(32, 8, 4), dim3(32, 8), 0, stream>>>((const float*)d_in[7], ff2wT, 1024, 256);

  for (int l = 0; l < 4; ++l) {
    // qkv = x @ qkv_w + b -> f16
    gemm_qkv<<<dim3(6, 128), 256, 0, stream>>>((const u16*)Xb, qkvwT + (size_t)l * 768 * 256,
        qkv_b + l * 768, qkvH, 8192, 768, 256);
    // attn
    attn_mfma<<<256, 512, 0, stream>>>(qkvH, attnB);
    // Xb = LN1(attn @ out_w + b + Xb)
    gemm_ln<<<256, 512, 0, stream>>>((const u16*)attnB, outwT + (size_t)l * 256 * 256,
        out_b + l * 256, Xb, ln1_g + l * 256, ln1_b + l * 256, Xb, nullptr, 256);
    // h = relu(Xb @ W1 + b1) -> bf16  (proven 128x128 structure, 512 blocks)
    gemm_relu<<<dim3(8, 64), 256, 0, stream>>>((const u16*)Xb, ff1wT + (size_t)l * 1024 * 256,
        ff1_b + l * 1024, hB, 8192, 1024, 256);
    // Xb = LN2(h @ W2 + b2 + Xb); last layer also writes d_out f32
    float* lnout = (l == 3) ? (float*)d_out : nullptr;
    gemm_ln<<<256, 512, 0, stream>>>((const u16*)hB, ff2wT + (size_t)l * 256 * 1024,
        ff2_b + l * 256, Xb, ln2_g + l * 256, ln2_b + l * 256, Xb, lnout, 1024);
  }
}

// Round 13
// 457.886 us; speedup vs baseline: 1.2226x; 1.0331x over previous
//
#include <hip/hip_runtime.h>
#include <hip/hip_bf16.h>
#include <stdint.h>

typedef unsigned short u16;
typedef _Float16 f16;
typedef short vs8 __attribute__((ext_vector_type(8)));   // 8 x bf16 bits (MFMA A/B frag)
typedef float vf4 __attribute__((ext_vector_type(4)));   // MFMA C/D frag
typedef _Float16 vh2 __attribute__((ext_vector_type(2)));
typedef _Float16 vh4 __attribute__((ext_vector_type(4)));
typedef _Float16 vh8 __attribute__((ext_vector_type(8)));
typedef __fp16 hw2 __attribute__((ext_vector_type(2)));  // cvt_pkrtz return type

// Problem constants: B=4 T=2048 E=256 H=8 HD=32 FE=4 L=4

__device__ __forceinline__ void gload16(const u16* g, u16* l) {
  __builtin_amdgcn_global_load_lds((const __attribute__((address_space(1))) void*)g,
                                   (__attribute__((address_space(3))) void*)l,
                                   16, 0, 0);
}

__device__ __forceinline__ float fexp2(float x) {
#if __has_builtin(__builtin_amdgcn_exp2f)
  return __builtin_amdgcn_exp2f(x);
#else
  return __expf(x * 0.69314718056f);
#endif
}

// ---------------- Fourier PE -> bf16 only ----------------
__global__ void pe_kernel(const float* __restrict__ x, __hip_bfloat16* __restrict__ Xb) {
  int row = blockIdx.x;            // b*2048 + t
  int e = threadIdx.x;             // 0..255
  int t = row & 2047;
  int f = (e < 128) ? e : (e - 128);
  float freq = powf(10000.0f, -(float)f * (1.0f / 128.0f));
  float arg = (float)t * freq;
  float pe = (e < 128) ? sinf(arg) : cosf(arg);
  size_t idx = (size_t)row * 256 + e;
  Xb[idx] = __float2bfloat16(x[idx] + pe);
}

// ---------------- weight transpose + cast: in[L][K][N] f32 -> out[L][N][K] bf16 ----------------
__global__ void transpose_cast(const float* __restrict__ in, u16* __restrict__ out,
                               int K, int N) {
  __shared__ float tile[32][33];
  int layer = blockIdx.z;
  int k0 = blockIdx.x * 32, n0 = blockIdx.y * 32;
  const float* ip = in + (size_t)layer * K * N;
  u16* op = out + (size_t)layer * N * K;
  int tx = threadIdx.x, ty = threadIdx.y;   // (32,8)
#pragma unroll
  for (int r = 0; r < 4; ++r) {
    int k = ty + r * 8;
    tile[k][tx] = ip[(size_t)(k0 + k) * N + (n0 + tx)];
  }
  __syncthreads();
#pragma unroll
  for (int r = 0; r < 4; ++r) {
    int n = ty + r * 8;
    __hip_bfloat16 v = __float2bfloat16(tile[tx][n]);
    op[(size_t)(n0 + n) * K + (k0 + tx)] = *(u16*)&v;
  }
}

// ---------------- bf16 MFMA GEMM 128x128 (ff1): C = relu(A@W + bias) -> bf16 ----------------
__global__ __launch_bounds__(256, 2) void gemm_relu(
    const u16* __restrict__ A, const u16* __restrict__ Bt,
    const float* __restrict__ bias, __hip_bfloat16* __restrict__ outB,
    int M, int N, int K) {
  __shared__ u16 As[128 * 32];
  __shared__ u16 Bs[128 * 32];
  int tid = threadIdx.x;
  int wave = tid >> 6, lane = tid & 63;
  int wm = wave & 1, wn = wave >> 1;              // 2x2 waves of 64x64
  int m0 = blockIdx.y * 128, n0 = blockIdx.x * 128;
  int lr = lane & 15, lq = lane >> 4;

  vf4 acc[4][4];
#pragma unroll
  for (int i = 0; i < 4; ++i)
#pragma unroll
    for (int j = 0; j < 4; ++j) {
      acc[i][j][0] = 0.f; acc[i][j][1] = 0.f; acc[i][j][2] = 0.f; acc[i][j][3] = 0.f;
    }

  int srow = wave * 16 + (lane >> 2);
  int scol = (lane & 3) * 8;
  const u16* ag = A + (size_t)(m0 + srow) * K + scol;
  const u16* bg = Bt + (size_t)(n0 + srow) * K + scol;
  u16* al = As + srow * 32 + scol;
  u16* bl = Bs + srow * 32 + scol;
  const size_t rstride = (size_t)64 * K;

  for (int k0 = 0; k0 < K; k0 += 32) {
    gload16(ag + k0, al);
    gload16(ag + k0 + rstride, al + 64 * 32);
    gload16(bg + k0, bl);
    gload16(bg + k0 + rstride, bl + 64 * 32);
    __syncthreads();
    vs8 av[4], bv[4];
#pragma unroll
    for (int i = 0; i < 4; ++i)
      av[i] = *(const vs8*)&As[(wm * 64 + i * 16 + lr) * 32 + lq * 8];
#pragma unroll
    for (int j = 0; j < 4; ++j)
      bv[j] = *(const vs8*)&Bs[(wn * 64 + j * 16 + lr) * 32 + lq * 8];
#pragma unroll
    for (int i = 0; i < 4; ++i)
#pragma unroll
      for (int j = 0; j < 4; ++j)
        acc[i][j] = __builtin_amdgcn_mfma_f32_16x16x32_bf16(av[i], bv[j], acc[i][j], 0, 0, 0);
    __syncthreads();
  }

#pragma unroll
  for (int i = 0; i < 4; ++i) {
    int row0 = m0 + wm * 64 + i * 16 + lq * 4;
#pragma unroll
    for (int j = 0; j < 4; ++j) {
      int col = n0 + wn * 64 + j * 16 + lr;
      float bb = bias[col];
#pragma unroll
      for (int r = 0; r < 4; ++r) {
        size_t idx = (size_t)(row0 + r) * N + col;
        outB[idx] = __float2bfloat16(fmaxf(acc[i][j][r] + bb, 0.0f));
      }
    }
  }
}

// ---------------- bf16 MFMA GEMM 64x128 (qkv): C = A@W + bias -> f16 ----------------
__global__ __launch_bounds__(256, 2) void gemm_qkv(
    const u16* __restrict__ A, const u16* __restrict__ Bt,
    const float* __restrict__ bias, f16* __restrict__ outH,
    int M, int N, int K) {
  __shared__ u16 As[64 * 32];
  __shared__ u16 Bs[128 * 32];
  int tid = threadIdx.x;
  int wave = tid >> 6, lane = tid & 63;
  int wm = wave & 1, wn = wave >> 1;              // wave = 32 rows x 64 cols
  int m0 = blockIdx.y * 64, n0 = blockIdx.x * 128;
  int lr = lane & 15, lq = lane >> 4;

  vf4 acc[2][4];
#pragma unroll
  for (int i = 0; i < 2; ++i)
#pragma unroll
    for (int j = 0; j < 4; ++j) { acc[i][j][0]=0.f; acc[i][j][1]=0.f; acc[i][j][2]=0.f; acc[i][j][3]=0.f; }

  int sr = tid >> 2, sc = (tid & 3) * 8;
  const u16* ag = A + (size_t)(m0 + sr) * K + sc;
  const u16* bg = Bt + (size_t)(n0 + sr) * K + sc;
  u16* al = As + sr * 32 + sc;
  u16* bl = Bs + sr * 32 + sc;

  for (int k0 = 0; k0 < K; k0 += 32) {
    gload16(ag + k0, al);
    gload16(bg + k0, bl);
    gload16(bg + k0 + (size_t)64 * K, bl + 64 * 32);
    __syncthreads();
    vs8 av[2], bv[4];
#pragma unroll
    for (int i = 0; i < 2; ++i)
      av[i] = *(const vs8*)&As[(wm * 32 + i * 16 + lr) * 32 + lq * 8];
#pragma unroll
    for (int j = 0; j < 4; ++j)
      bv[j] = *(const vs8*)&Bs[(wn * 64 + j * 16 + lr) * 32 + lq * 8];
#pragma unroll
    for (int i = 0; i < 2; ++i)
#pragma unroll
      for (int j = 0; j < 4; ++j)
        acc[i][j] = __builtin_amdgcn_mfma_f32_16x16x32_bf16(av[i], bv[j], acc[i][j], 0, 0, 0);
    __syncthreads();
  }

#pragma unroll
  for (int i = 0; i < 2; ++i) {
    int row0 = m0 + wm * 32 + i * 16 + lq * 4;
#pragma unroll
    for (int j = 0; j < 4; ++j) {
      int col = n0 + wn * 64 + j * 16 + lr;
      float bb = bias[col];
#pragma unroll
      for (int r = 0; r < 4; ++r)
        outH[(size_t)(row0 + r) * N + col] = (f16)(acc[i][j][r] + bb);
    }
  }
}

// ---------------- fused GEMM (N=256) + bias + bf16 residual + LN -> bf16 (+f32 opt) ----------------
// 512 threads = 8 waves (wm 2 x wn 4); wave = 16 rows x 64 cols. Grid 256, 8 waves/CU.
__global__ __launch_bounds__(512, 2) void gemm_ln(
    const u16* __restrict__ A, const u16* __restrict__ Bt,
    const float* __restrict__ bias, const __hip_bfloat16* __restrict__ res,
    const float* __restrict__ gam, const float* __restrict__ bet,
    __hip_bfloat16* __restrict__ outB, float* __restrict__ outF, int K) {
  __shared__ u16 As[32 * 32];
  __shared__ u16 Bs[256 * 32];
  __shared__ float ps[4][32], ps2[4][32], mur[32], rsr[32];
  int tid = threadIdx.x;
  int wave = tid >> 6, lane = tid & 63;
  int wm = wave & 1, wn = wave >> 1;              // wn 0..3
  int lr = lane & 15, lq = lane >> 4;
  int m0 = blockIdx.x * 32;

  vf4 acc[4];
#pragma unroll
  for (int j = 0; j < 4; ++j) { acc[j][0]=0.f; acc[j][1]=0.f; acc[j][2]=0.f; acc[j][3]=0.f; }

  int sr = tid >> 2, sc = (tid & 3) * 8;          // sr 0..127
  const u16* ag = A + (size_t)(m0 + sr) * K + sc; // deref only for tid<128 (rows 0..31)
  const u16* bg = Bt + (size_t)sr * K + sc;       // rows 0..127; +128 for round 2
  u16* al = As + sr * 32 + sc;
  u16* bl = Bs + sr * 32 + sc;

  for (int k0 = 0; k0 < K; k0 += 32) {
    if (tid < 128) gload16(ag + k0, al);
    gload16(bg + k0, bl);
    gload16(bg + k0 + (size_t)128 * K, bl + 128 * 32);
    __syncthreads();
    vs8 av, bv[4];
    av = *(const vs8*)&As[(wm * 16 + lr) * 32 + lq * 8];
#pragma unroll
    for (int j = 0; j < 4; ++j)
      bv[j] = *(const vs8*)&Bs[(wn * 64 + j * 16 + lr) * 32 + lq * 8];
#pragma unroll
    for (int j = 0; j < 4; ++j)
      acc[j] = __builtin_amdgcn_mfma_f32_16x16x32_bf16(av, bv[j], acc[j], 0, 0, 0);
    __syncthreads();
  }

  float sum_[4], sq_[4];
#pragma unroll
  for (int r = 0; r < 4; ++r) { sum_[r] = 0.f; sq_[r] = 0.f; }
#pragma unroll
  for (int j = 0; j < 4; ++j) {
    int col = wn * 64 + j * 16 + lr;
    float bb = bias[col];
#pragma unroll
    for (int r = 0; r < 4; ++r) {
      int row = m0 + wm * 16 + lq * 4 + r;
      float v = acc[j][r] + bb + __bfloat162float(res[(size_t)row * 256 + col]);
      acc[j][r] = v;
      sum_[r] += v;
      sq_[r] += v * v;
    }
  }
#pragma unroll
  for (int r = 0; r < 4; ++r) {
#pragma unroll
    for (int m = 1; m <= 8; m <<= 1) {
      sum_[r] += __shfl_xor(sum_[r], m);
      sq_[r]  += __shfl_xor(sq_[r], m);
    }
  }
  if (lr == 0) {
#pragma unroll
    for (int r = 0; r < 4; ++r) {
      int rl = wm * 16 + lq * 4 + r;
      ps[wn][rl] = sum_[r];
      ps2[wn][rl] = sq_[r];
    }
  }
  __syncthreads();
  if (tid < 32) {
    float s = ps[0][tid] + ps[1][tid] + ps[2][tid] + ps[3][tid];
    float s2 = ps2[0][tid] + ps2[1][tid] + ps2[2][tid] + ps2[3][tid];
    float mu = s * (1.0f / 256.0f);
    float var = s2 * (1.0f / 256.0f) - mu * mu;
    mur[tid] = mu;
    rsr[tid] = rsqrtf(var + 1e-5f);
  }
  __syncthreads();
#pragma unroll
  for (int r = 0; r < 4; ++r) {
    int rl = wm * 16 + lq * 4 + r;
    float mu = mur[rl], rs = rsr[rl];
    int row = m0 + rl;
#pragma unroll
    for (int j = 0; j < 4; ++j) {
      int col = wn * 64 + j * 16 + lr;
      float o = (acc[j][r] - mu) * rs * gam[col] + bet[col];
      size_t idx = (size_t)row * 256 + col;
      outB[idx] = __float2bfloat16(o);
      if (outF) outF[idx] = o;
    }
  }
}

// ---------------- MFMA flash attention v6: kv-chunk 128 (latency amortization) ----------------
// R12 post-mortem: attn is ~5x above its throughput floor — latency/barrier-bound at 8 waves/CU
// (occupancy structurally capped: 2048 waves total at 32 q-rows/wave). Fix: double kv-chunk to
// 128 rows -> compute/barrier ~800-1000 cyc > prefetch latency (~200-900); barriers 32 -> 16.
// Same q-tiling (8 waves x 32 q rows, grid 256 XCD-pinned), same frag paths, same bank patterns.
__global__ __launch_bounds__(512, 4) void attn_mfma(const f16* __restrict__ qkv,
                                                    __hip_bfloat16* __restrict__ out) {
  // per buf: K [128][40] u16 = 5120 | VT [32][132] f16 = 4224 -> 9344 u16; x2 bufs = 37376 B
  __shared__ __align__(16) u16 lds[2][9344];
  int tid = threadIdx.x;
  int wave = tid >> 6, lane = tid & 63;
  int lr = lane & 15, quad = lane >> 4;

  int id = blockIdx.x;
  int xcd = id & 7, slot = id >> 3;
  int grp = xcd * 4 + (slot & 3);
  int qt = slot >> 2;
  int b = grp >> 3, h = grp & 7;
  int q0 = qt * 256;
  int rowbase = b * 2048;
  const f16* base_bh = qkv + (size_t)rowbase * 768 + h * 96;

  vh8 qf[2];
#pragma unroll
  for (int nt = 0; nt < 2; ++nt) {
    int qr = q0 + wave * 32 + nt * 16 + lr;
    vh8 t = *(const vh8*)(base_bh + (size_t)qr * 768 + quad * 8);
#pragma unroll
    for (int j = 0; j < 8; ++j) t[j] = t[j] * (f16)0.25508682f;
    qf[nt] = t;
  }

  vf4 O[2][2], lO[2];
#pragma unroll
  for (int a = 0; a < 2; ++a) {
    lO[a][0]=0.f; lO[a][1]=0.f; lO[a][2]=0.f; lO[a][3]=0.f;
#pragma unroll
    for (int d = 0; d < 2; ++d) { O[a][d][0]=0.f; O[a][d][1]=0.f; O[a][d][2]=0.f; O[a][d][3]=0.f; }
  }

  // staging maps: all 512 threads stage K (1 vh8) and V (2 vh4 -> 4 vh2) per chunk
  int srK = tid >> 2;                  // 0..127
  int scK = (tid & 3) * 8;
  const f16* kg = base_bh + (size_t)srK * 768 + 32 + scK;
  int kvp = tid >> 3;                  // 0..63 -> rows 2kvp, 2kvp+1
  int d4 = (tid & 7) * 4;
  const f16* vg = base_bh + (size_t)(kvp * 2) * 768 + 64 + d4;

  const vf4 z4 = {0.f, 0.f, 0.f, 0.f};
  const vh4 onesh = {(f16)1.0f, (f16)1.0f, (f16)1.0f, (f16)1.0f};
  const size_t cstep = (size_t)128 * 768;

  // stage chunk 0 into buf 0
  {
    vh8 k0 = *(const vh8*)kg;
    *(vh8*)&lds[0][srK * 40 + scK] = k0;
    vh4 a = *(const vh4*)vg;
    vh4 bb = *(const vh4*)(vg + 768);
    f16* vt0 = (f16*)&lds[0][5120];
#pragma unroll
    for (int i = 0; i < 4; ++i) {
      vh2 pr; pr[0] = a[i]; pr[1] = bb[i];
      *(vh2*)(vt0 + (d4 + i) * 132 + kvp * 2) = pr;
    }
  }
  __syncthreads();

  for (int c = 0; c < 16; ++c) {
    int cur = c & 1;
    const f16* Ks = (const f16*)&lds[cur][0];
    const f16* VT = (const f16*)&lds[cur][5120];

    vh8 kn; vh4 va, vb;
    if (c < 15) {                      // prefetch next chunk (hidden under 8-t16 compute)
      kn = *(const vh8*)(kg + (size_t)(c + 1) * cstep);
      const f16* vp = vg + (size_t)(c + 1) * cstep;
      va = *(const vh4*)vp;
      vb = *(const vh4*)(vp + 768);
    }

#pragma unroll
    for (int t16 = 0; t16 < 8; ++t16) {
      vh8 ak = *(const vh8*)&Ks[(t16 * 16 + lr) * 40 + quad * 8];
      vf4 s0 = __builtin_amdgcn_mfma_f32_16x16x32_f16(ak, qf[0], z4, 0, 0, 0);
      vf4 s1 = __builtin_amdgcn_mfma_f32_16x16x32_f16(ak, qf[1], z4, 0, 0, 0);
      vh4 p0, p1;
      ((hw2*)&p0)[0] = __builtin_amdgcn_cvt_pkrtz(fexp2(s0[0]), fexp2(s0[1]));
      ((hw2*)&p0)[1] = __builtin_amdgcn_cvt_pkrtz(fexp2(s0[2]), fexp2(s0[3]));
      ((hw2*)&p1)[0] = __builtin_amdgcn_cvt_pkrtz(fexp2(s1[0]), fexp2(s1[1]));
      ((hw2*)&p1)[1] = __builtin_amdgcn_cvt_pkrtz(fexp2(s1[2]), fexp2(s1[3]));
      vh4 vf0 = *(const vh4*)&VT[(0 * 16 + lr) * 132 + t16 * 16 + quad * 4];
      vh4 vf1 = *(const vh4*)&VT[(1 * 16 + lr) * 132 + t16 * 16 + quad * 4];
      O[0][0] = __builtin_amdgcn_mfma_f32_16x16x16f16(p0, vf0, O[0][0], 0, 0, 0);
      O[0][1] = __builtin_amdgcn_mfma_f32_16x16x16f16(p0, vf1, O[0][1], 0, 0, 0);
      O[1][0] = __builtin_amdgcn_mfma_f32_16x16x16f16(p1, vf0, O[1][0], 0, 0, 0);
      O[1][1] = __builtin_amdgcn_mfma_f32_16x16x16f16(p1, vf1, O[1][1], 0, 0, 0);
      lO[0] = __builtin_amdgcn_mfma_f32_16x16x16f16(p0, onesh, lO[0], 0, 0, 0);
      lO[1] = __builtin_amdgcn_mfma_f32_16x16x16f16(p1, onesh, lO[1], 0, 0, 0);
    }

    if (c < 15) {                      // write prefetched chunk into the other buffer
      *(vh8*)&lds[cur ^ 1][srK * 40 + scK] = kn;
      f16* vt1 = (f16*)&lds[cur ^ 1][5120];
#pragma unroll
      for (int i = 0; i < 4; ++i) {
        vh2 pr; pr[0] = va[i]; pr[1] = vb[i];
        *(vh2*)(vt1 + (d4 + i) * 132 + kvp * 2) = pr;
      }
    }
    __syncthreads();
  }

  // epilogue: l lane-aligned with O (row q = quad*4+r)
#pragma unroll
  for (int nt = 0; nt < 2; ++nt) {
#pragma unroll
    for (int r = 0; r < 4; ++r) {
      float inv = 1.0f / lO[nt][r];
      int row = rowbase + q0 + wave * 32 + nt * 16 + quad * 4 + r;
#pragma unroll
      for (int dt = 0; dt < 2; ++dt) {
        int col = h * 32 + dt * 16 + lr;
        out[(size_t)row * 256 + col] = __float2bfloat16(O[nt][dt][r] * inv);
      }
    }
  }
}

// ---------------- driver ----------------
extern "C" void kernel_launch(void* const* d_in, const int* in_sizes, int n_in,
                              void* d_out, int out_size, void* d_ws, size_t ws_size,
                              hipStream_t stream) {
  (void)in_sizes; (void)n_in; (void)out_size; (void)ws_size;
  const float* x     = (const float*)d_in[0];
  const float* qkv_b = (const float*)d_in[2];
  const float* out_b = (const float*)d_in[4];
  const float* ff1_b = (const float*)d_in[6];
  const float* ff2_b = (const float*)d_in[8];
  const float* ln1_g = (const float*)d_in[9];
  const float* ln1_b = (const float*)d_in[10];
  const float* ln2_g = (const float*)d_in[11];
  const float* ln2_b = (const float*)d_in[12];

  // ws layout (bytes); total = 44,040,192
  char* ws = (char*)d_ws;
  __hip_bfloat16* Xb    = (__hip_bfloat16*)(ws + 8388608);     // bf16 x (carried state, 4 MB)
  __hip_bfloat16* attnB = (__hip_bfloat16*)(ws + 20971520);    // attn out bf16 (4 MB)
  f16*            qkvH  = (f16*)(ws + 25165824);               // 8192x768 f16 (12.6 MB)
  __hip_bfloat16* hB    = (__hip_bfloat16*)(ws + 20971520);    // ff1 out bf16 (16.8 MB) overlaps attnB+qkvH (both dead by ff1)
  u16* qkvwT = (u16*)(ws + 37748736);  // [L][768][256] bf16
  u16* outwT = (u16*)(ws + 39321600);  // [L][256][256] bf16
  u16* ff1wT = (u16*)(ws + 39845888);  // [L][1024][256] bf16
  u16* ff2wT = (u16*)(ws + 41943040);  // [L][256][1024] bf16  ends 44,040,192

  pe_kernel<<<8192, 256, 0, stream>>>(x, Xb);
  transpose_cast<<<dim3(8, 24, 4), dim3(32, 8), 0, stream>>>((const float*)d_in[1], qkvwT, 256, 768);
  transpose_cast<<<dim3(8, 8, 4),  dim3(32, 8), 0, stream>>>((const float*)d_in[3], outwT, 256, 256);
  transpose_cast<<<dim3(8, 32, 4), dim3(32, 8), 0, stream>>>((const float*)d_in[5], ff1wT, 256, 1024);
  transpose_cast<<<dim3(32, 8, 4), dim3(32, 8), 0, stream>>>((const float*)d_in[7], ff2wT, 1024, 256);

  for (int l = 0; l < 4; ++l) {
    // qkv = x @ qkv_w + b -> f16
    gemm_qkv<<<dim3(6, 128), 256, 0, stream>>>((const u16*)Xb, qkvwT + (size_t)l * 768 * 256,
        qkv_b + l * 768, qkvH, 8192, 768, 256);
    // attn (kv-chunk 128, XCD-pinned)
    attn_mfma<<<256, 512, 0, stream>>>(qkvH, attnB);
    // Xb = LN1(attn @ out_w + b + Xb)
    gemm_ln<<<256, 512, 0, stream>>>((const u16*)attnB, outwT + (size_t)l * 256 * 256,
        out_b + l * 256, Xb, ln1_g + l * 256, ln1_b + l * 256, Xb, nullptr, 256);
    // h = relu(Xb @ W1 + b1) -> bf16
    gemm_relu<<<dim3(8, 64), 256, 0, stream>>>((const u16*)Xb, ff1wT + (size_t)l * 1024 * 256,
        ff1_b + l * 1024, hB, 8192, 1024, 256);
    // Xb = LN2(h @ W2 + b2 + Xb); last layer also writes d_out f32
    float* lnout = (l == 3) ? (float*)d_out : nullptr;
    gemm_ln<<<256, 512, 0, stream>>>((const u16*)hB, ff2wT + (size_t)l * 256 * 1024,
        ff2_b + l * 256, Xb, ln2_g + l * 256, ln2_b + l * 256, Xb, lnout, 1024);
  }
}